// Round 5
// baseline (577.334 us; speedup 1.0000x reference)
//
#include <hip/hip_runtime.h>
#include <hip/hip_bf16.h>

constexpr int Bc = 32;    // batch
constexpr int Sc = 2048;  // sequence length
constexpr int Tc = 64;    // tables
constexpr int Cc = 512;   // columns
constexpr int Lc = 16;    // tokens per span
constexpr int Dc = 768;   // hidden
constexpr int Hc = 8;     // heads
constexpr int DHc = 96;   // head dim

typedef __attribute__((ext_vector_type(4))) float f32x4;
typedef __attribute__((ext_vector_type(8))) short bf16x8;  // 8 bf16 in 4 VGPRs
typedef __hip_bfloat16 bf;

__device__ inline unsigned short f2bf(float f) {
  __hip_bfloat16 h = __float2bfloat16(f);
  return *reinterpret_cast<unsigned short*>(&h);
}
__device__ inline float us2f(unsigned short u) {
  return __uint_as_float(((unsigned)u) << 16);
}

#define GLDS16(gp, lp)                                                        \
  __builtin_amdgcn_global_load_lds(                                           \
      (const __attribute__((address_space(1))) void*)(gp),                    \
      (__attribute__((address_space(3))) void*)(lp), 16, 0, 0)

// ---------------------------------------------------------------------------
// 0) Fused prep (one launch, region-dispatched by blockIdx.x):
//    [0,576)        W_tab_pool 768x768 [K][N] -> bf16 [N][K]
//    [576,1152)     W_col_pool  "
//    [1152,1344)    W_t1 768x256 -> bf16 [256][768]
//    [1344,1536)    W_c1 768x256 -> bf16 [256][768]
//    [1536,3264)    in_proj  f32->bf16 (already [N][K])
//    [3264,3840)    out_proj f32->bf16
//    [3840,3984)    d_out init with head biases (atomic targets)
//    [3984,28560)   seq f32 -> bf16
//    [28560,28592)  bucket (one block per batch)
//    [28592]        zero ssq (row sum-of-squares accumulators)
// ---------------------------------------------------------------------------
__device__ inline void transpose32(const float* __restrict__ in,
                                   bf* __restrict__ outp, int K, int N,
                                   int ti, float (*t)[33]) {
  int nx = N >> 5;
  int bx = (ti % nx) * 32, by = (ti / nx) * 32;
  int x = threadIdx.x & 31, y = threadIdx.x >> 5;  // 32 x 8
#pragma unroll
  for (int i = 0; i < 32; i += 8)
    t[y + i][x] = in[(size_t)(by + y + i) * N + bx + x];
  __syncthreads();
#pragma unroll
  for (int i = 0; i < 32; i += 8)
    outp[(size_t)(bx + y + i) * K + by + x] = __float2bfloat16(t[x][y + i]);
}

__global__ __launch_bounds__(256) void prep_kernel(
    const float* __restrict__ W_tab_pool, const float* __restrict__ W_col_pool,
    const float* __restrict__ W_t1, const float* __restrict__ W_c1,
    const float* __restrict__ in_proj_w, const float* __restrict__ out_proj_w,
    const float* __restrict__ b_t2, const float* __restrict__ b_c2,
    const float* __restrict__ seq, const int* __restrict__ t_of_c,
    bf* __restrict__ wtab_t, bf* __restrict__ wcol_t, bf* __restrict__ wt1_t,
    bf* __restrict__ wc1_t, bf* __restrict__ winproj, bf* __restrict__ woutproj,
    float* __restrict__ outd, ushort* __restrict__ seqb,
    int* __restrict__ col_sorted, int* __restrict__ offs,
    float* __restrict__ ssq) {
  __shared__ float t[32][33];
  __shared__ int cnt[Tc];
  __shared__ int cur[Tc + 1];
  int blk = blockIdx.x, tid = threadIdx.x;
  if (blk < 576) {
    transpose32(W_tab_pool, wtab_t, Dc, Dc, blk, t);
  } else if (blk < 1152) {
    transpose32(W_col_pool, wcol_t, Dc, Dc, blk - 576, t);
  } else if (blk < 1344) {
    transpose32(W_t1, wt1_t, Dc, 256, blk - 1152, t);
  } else if (blk < 1536) {
    transpose32(W_c1, wc1_t, Dc, 256, blk - 1344, t);
  } else if (blk < 3264) {
    int i = (blk - 1536) * 256 + tid;
    float4 v = reinterpret_cast<const float4*>(in_proj_w)[i];
    reinterpret_cast<ushort4*>(winproj)[i] =
        make_ushort4(f2bf(v.x), f2bf(v.y), f2bf(v.z), f2bf(v.w));
  } else if (blk < 3840) {
    int i = (blk - 3264) * 256 + tid;
    float4 v = reinterpret_cast<const float4*>(out_proj_w)[i];
    reinterpret_cast<ushort4*>(woutproj)[i] =
        make_ushort4(f2bf(v.x), f2bf(v.y), f2bf(v.z), f2bf(v.w));
  } else if (blk < 3984) {
    int e = (blk - 3840) * 256 + tid;  // < 36864
    int i = e & 1;
    int r = (e >> 1) % (Tc + Cc);
    outd[e] = (r < Tc) ? b_t2[i] : b_c2[i];
  } else if (blk < 28560) {
    int i0 = (blk - 3984) * 512 + tid;
    const float4* s4 = reinterpret_cast<const float4*>(seq);
    ushort4* o4 = reinterpret_cast<ushort4*>(seqb);
    float4 v = s4[i0];
    o4[i0] = make_ushort4(f2bf(v.x), f2bf(v.y), f2bf(v.z), f2bf(v.w));
    float4 v2 = s4[i0 + 256];
    o4[i0 + 256] = make_ushort4(f2bf(v2.x), f2bf(v2.y), f2bf(v2.z), f2bf(v2.w));
  } else if (blk < 28592) {
    // bucket: one block per batch
    int b = blk - 28560;
    if (tid < Tc) cnt[tid] = 0;
    __syncthreads();
    for (int c = tid; c < Cc; c += 256) atomicAdd(&cnt[t_of_c[b * Cc + c]], 1);
    __syncthreads();
    if (tid == 0) {
      int off = 0;
      for (int tt = 0; tt < Tc; ++tt) {
        cur[tt] = off;
        off += cnt[tt];
      }
      cur[Tc] = off;
    }
    __syncthreads();
    if (tid <= Tc) offs[b * (Tc + 1) + tid] = cur[tid];
    __syncthreads();
    for (int c = tid; c < Cc; c += 256) {
      int tt = t_of_c[b * Cc + c];
      int pos = atomicAdd(&cur[tt], 1);
      col_sorted[b * Cc + pos] = c;
    }
  } else {
#pragma unroll
    for (int i = 0; i < 8; ++i) ssq[tid * 8 + i] = 0.f;
  }
}

// ---------------------------------------------------------------------------
// 1) Ragged gather + sum pooling from bf16 seq, XCD-chunked swizzle.
// ---------------------------------------------------------------------------
__global__ __launch_bounds__(256) void pool_kernel(
    const ushort* __restrict__ seqb, const int* __restrict__ tab_ids,
    const int* __restrict__ col_ids, ushort* __restrict__ tabp,
    ushort* __restrict__ colp) {
  int swz = (blockIdx.x & 7) * 576 + (blockIdx.x >> 3);
  int w = threadIdx.x >> 6, l = threadIdx.x & 63;
  int row = swz * 4 + w;
  int b = row / (Tc + Cc), r = row % (Tc + Cc);
  const int* ids;
  ushort* outp;
  if (r < Tc) {
    ids = tab_ids + ((size_t)b * Tc + r) * Lc;
    outp = tabp + ((size_t)b * Tc + r) * Dc;
  } else {
    int c = r - Tc;
    ids = col_ids + ((size_t)b * Cc + c) * Lc;
    outp = colp + ((size_t)b * Cc + c) * Dc;
  }
  float a0[4] = {0, 0, 0, 0}, a1[4] = {0, 0, 0, 0}, a2[4] = {0, 0, 0, 0};
#pragma unroll
  for (int tix = 0; tix < Lc; ++tix) {
    const ushort4* p =
        reinterpret_cast<const ushort4*>(seqb + ((size_t)b * Sc + ids[tix]) * Dc);
    ushort4 u0 = p[l], u1 = p[l + 64], u2 = p[l + 128];
    a0[0] += us2f(u0.x); a0[1] += us2f(u0.y); a0[2] += us2f(u0.z); a0[3] += us2f(u0.w);
    a1[0] += us2f(u1.x); a1[1] += us2f(u1.y); a1[2] += us2f(u1.z); a1[3] += us2f(u1.w);
    a2[0] += us2f(u2.x); a2[1] += us2f(u2.y); a2[2] += us2f(u2.z); a2[3] += us2f(u2.w);
  }
  ushort4* ob = reinterpret_cast<ushort4*>(outp);
  ob[l] = make_ushort4(f2bf(a0[0]), f2bf(a0[1]), f2bf(a0[2]), f2bf(a0[3]));
  ob[l + 64] = make_ushort4(f2bf(a1[0]), f2bf(a1[1]), f2bf(a1[2]), f2bf(a1[3]));
  ob[l + 128] = make_ushort4(f2bf(a2[0]), f2bf(a2[1]), f2bf(a2[2]), f2bf(a2[3]));
}

// ---------------------------------------------------------------------------
// 2) bf16 MFMA GEMM core, DOUBLE-BUFFERED 2-phase (T3 minimum recipe):
//    prologue-stage buf0; loop { issue stage(buf^1, next) BEFORE ds_read+MFMA
//    of buf; one barrier }. The compiler's vmcnt(0)-at-barrier then waits on
//    loads that had a full compute phase to land. K=768 fixed. 64 KB LDS.
//    outmode: 0 bf16 out; 2 bf16 out + optional f32 out;
//             3 fused head: atomicAdd(leaky(scale*acc+b) @ w2) into outd;
//             4 outproj+residual+norm-prep: x = acc+b+tabf, write bf16 x,
//               atomicAdd per-row sum(x^2) into ssq.
// ---------------------------------------------------------------------------
__device__ __forceinline__ void gemm_core(
    const bf* __restrict__ A, const bf* __restrict__ Bt,
    const float* __restrict__ bias, bf* __restrict__ Obf,
    float* __restrict__ Of32, const float* __restrict__ w2,
    float* __restrict__ outd, int out_base, int log2rpb,
    const float* __restrict__ tabf, float* __restrict__ ssq,
    const float* __restrict__ ssrd, int bx, int by, int N, int leaky,
    int outmode) {
  constexpr int BM = 128, BN = 128, BK = 64, K = Dc;
  __shared__ bf As[2][BM * BK];
  __shared__ bf Bs[2][BN * BK];
  int tid = threadIdx.x;
  int row0 = by * BM, col0 = bx * BN;
  int w = tid >> 6, l = tid & 63;
  int wr = (w >> 1) * 64, wc = (w & 1) * 64;
  f32x4 acc[4][4];
#pragma unroll
  for (int m = 0; m < 4; ++m)
#pragma unroll
    for (int n = 0; n < 4; ++n) acc[m][n] = f32x4{0.f, 0.f, 0.f, 0.f};

  int srow = tid >> 3, skk = (tid & 7) * 8;
  const bf* gA = A + (size_t)(row0 + srow) * K + skk;
  const bf* gB = Bt + (size_t)(col0 + srow) * K + skk;
  char* lA = (char*)&As[0][0] + tid * 16;
  char* lB = (char*)&Bs[0][0] + tid * 16;
  int lr = l & 15, lk = (l >> 4) * 8;

  // prologue: stage buf 0 (tile k0=0)
#pragma unroll
  for (int c = 0; c < 4; ++c) {
    GLDS16(gA + (size_t)c * 32 * K, lA + c * 4096);
    GLDS16(gB + (size_t)c * 32 * K, lB + c * 4096);
  }
  __syncthreads();
  int cur = 0;
  for (int k0 = 0; k0 < K; k0 += BK) {
    if (k0 + BK < K) {  // issue next tile's stage into the other buffer
      int nb = cur ^ 1;
#pragma unroll
      for (int c = 0; c < 4; ++c) {
        GLDS16(gA + k0 + BK + (size_t)c * 32 * K, lA + nb * 16384 + c * 4096);
        GLDS16(gB + k0 + BK + (size_t)c * 32 * K, lB + nb * 16384 + c * 4096);
      }
    }
    bf16x8 af[2][4], bfr[2][4];
#pragma unroll
    for (int ks = 0; ks < 2; ++ks) {
#pragma unroll
      for (int m = 0; m < 4; ++m)
        af[ks][m] = *reinterpret_cast<const bf16x8*>(
            &As[cur][(wr + m * 16 + lr) * BK + ks * 32 + lk]);
#pragma unroll
      for (int n = 0; n < 4; ++n)
        bfr[ks][n] = *reinterpret_cast<const bf16x8*>(
            &Bs[cur][(wc + n * 16 + lr) * BK + ks * 32 + lk]);
    }
#pragma unroll
    for (int ks = 0; ks < 2; ++ks)
#pragma unroll
      for (int m = 0; m < 4; ++m)
#pragma unroll
        for (int n = 0; n < 4; ++n)
          acc[m][n] = __builtin_amdgcn_mfma_f32_16x16x32_bf16(
              af[ks][m], bfr[ks][n], acc[m][n], 0, 0, 0);
    if (k0 + BK < K) __syncthreads();  // next buf staged; reads of cur done
    cur ^= 1;
  }

  // C/D layout: col = lane&15, row = (lane>>4)*4 + reg
  int colI = l & 15, rowb = (l >> 4) * 4;
  if (outmode == 3) {
    float w20[4], w21[4], bv[4];
#pragma unroll
    for (int n = 0; n < 4; ++n) {
      int c = col0 + wc + n * 16 + colI;
      w20[n] = w2[c * 2];
      w21[n] = w2[c * 2 + 1];
      bv[n] = bias[c];
    }
    float scr[4][4];
#pragma unroll
    for (int m = 0; m < 4; ++m)
#pragma unroll
      for (int j = 0; j < 4; ++j) {
        if (ssrd) {
          int r = row0 + wr + m * 16 + rowb + j;
          scr[m][j] = 1.f / fmaxf(sqrtf(ssrd[r]), 1e-12f);
        } else {
          scr[m][j] = 1.f;
        }
      }
    float p0[4][4], p1[4][4];
#pragma unroll
    for (int m = 0; m < 4; ++m)
#pragma unroll
      for (int j = 0; j < 4; ++j) { p0[m][j] = 0.f; p1[m][j] = 0.f; }
#pragma unroll
    for (int m = 0; m < 4; ++m)
#pragma unroll
      for (int n = 0; n < 4; ++n)
#pragma unroll
        for (int j = 0; j < 4; ++j) {
          float v = scr[m][j] * acc[m][n][j] + bv[n];
          v = v >= 0.f ? v : 0.01f * v;  // leaky always on for heads
          p0[m][j] += v * w20[n];
          p1[m][j] += v * w21[n];
        }
#pragma unroll
    for (int m = 0; m < 4; ++m)
#pragma unroll
      for (int j = 0; j < 4; ++j) {
#pragma unroll
        for (int msk = 1; msk <= 8; msk <<= 1) {
          p0[m][j] += __shfl_xor(p0[m][j], msk);
          p1[m][j] += __shfl_xor(p1[m][j], msk);
        }
      }
    if (colI == 0) {
#pragma unroll
      for (int m = 0; m < 4; ++m)
#pragma unroll
        for (int j = 0; j < 4; ++j) {
          int grow = row0 + wr + m * 16 + rowb + j;
          int bb = grow >> log2rpb;
          int rr = grow & ((1 << log2rpb) - 1);
          int orow = bb * (Tc + Cc) + out_base + rr;
          atomicAdd(&outd[(size_t)orow * 2], p0[m][j]);
          atomicAdd(&outd[(size_t)orow * 2 + 1], p1[m][j]);
        }
    }
    return;
  }
  if (outmode == 4) {
    float sq[4][4];
#pragma unroll
    for (int m = 0; m < 4; ++m)
#pragma unroll
      for (int j = 0; j < 4; ++j) sq[m][j] = 0.f;
#pragma unroll
    for (int m = 0; m < 4; ++m)
#pragma unroll
      for (int n = 0; n < 4; ++n) {
        int c = col0 + wc + n * 16 + colI;
        float bv = bias[c];
#pragma unroll
        for (int j = 0; j < 4; ++j) {
          int r = row0 + wr + m * 16 + rowb + j;
          float x = acc[m][n][j] + bv + tabf[(size_t)r * N + c];
          Obf[(size_t)r * N + c] = __float2bfloat16(x);
          sq[m][j] += x * x;
        }
      }
#pragma unroll
    for (int m = 0; m < 4; ++m)
#pragma unroll
      for (int j = 0; j < 4; ++j) {
#pragma unroll
        for (int msk = 1; msk <= 8; msk <<= 1)
          sq[m][j] += __shfl_xor(sq[m][j], msk);
      }
    if (colI == 0) {
#pragma unroll
      for (int m = 0; m < 4; ++m)
#pragma unroll
        for (int j = 0; j < 4; ++j)
          atomicAdd(&ssq[row0 + wr + m * 16 + rowb + j], sq[m][j]);
    }
    return;
  }
#pragma unroll
  for (int m = 0; m < 4; ++m) {
#pragma unroll
    for (int n = 0; n < 4; ++n) {
      int c = col0 + wc + n * 16 + colI;
      float bv = bias ? bias[c] : 0.f;
#pragma unroll
      for (int j = 0; j < 4; ++j) {
        int r = row0 + wr + m * 16 + rowb + j;
        float v = acc[m][n][j] + bv;
        if (leaky) v = v >= 0.f ? v : 0.01f * v;
        Obf[(size_t)r * N + c] = __float2bfloat16(v);
        if (outmode == 2 && Of32) Of32[(size_t)r * N + c] = v;
      }
    }
  }
}

// Launch A: tab pool-linear (96) + col pool-linear (768). 864 = 8*108.
__global__ __launch_bounds__(256) void gemm_pools(
    const bf* __restrict__ tabp, const bf* __restrict__ colp,
    const bf* __restrict__ wtab_t, const bf* __restrict__ wcol_t,
    const float* __restrict__ b_tab, const float* __restrict__ b_col,
    bf* __restrict__ tabb_bf, float* __restrict__ tabb_f,
    bf* __restrict__ colb) {
  int id = (blockIdx.x & 7) * 108 + (blockIdx.x >> 3);
  const bf* Aa; const bf* Bb; const float* bb; bf* Oo; float* Ff;
  int bx, by;
  if (id < 96) {
    Aa = tabp; Bb = wtab_t; bb = b_tab; Oo = tabb_bf; Ff = tabb_f;
    bx = id % 6; by = id / 6;
  } else {
    int r = id - 96;
    Aa = colp; Bb = wcol_t; bb = b_col; Oo = colb; Ff = nullptr;
    bx = r % 6; by = r / 6;
  }
  gemm_core(Aa, Bb, bb, Oo, Ff, nullptr, nullptr, 0, 0, nullptr, nullptr,
            nullptr, bx, by, Dc, 1, 2);
}

// Launch B: q (96) + fused kv (1536). 1632 = 8*204.
__global__ __launch_bounds__(256) void gemm_qkv(
    const bf* __restrict__ tabb_bf, const bf* __restrict__ colb,
    const bf* __restrict__ winproj, const float* __restrict__ in_proj_b,
    bf* __restrict__ qb, bf* __restrict__ kvb) {
  int id = (blockIdx.x & 7) * 204 + (blockIdx.x >> 3);
  const bf* Aa; const bf* Bb; const float* bb; bf* Oo;
  int bx, by, NN;
  if (id < 96) {
    Aa = tabb_bf; Bb = winproj; bb = in_proj_b; Oo = qb;
    bx = id % 6; by = id / 6; NN = Dc;
  } else {
    int r = id - 96;
    Aa = colb; Bb = winproj + (size_t)Dc * Dc; bb = in_proj_b + Dc; Oo = kvb;
    bx = r % 12; by = r / 12; NN = 1536;
  }
  gemm_core(Aa, Bb, bb, Oo, nullptr, nullptr, nullptr, 0, 0, nullptr, nullptr,
            nullptr, bx, by, NN, 0, 0);
}

// Launch C (post-attn): outproj+residual+norm-prep (96) + c1 head (256).
__global__ __launch_bounds__(256) void gemm_oc(
    const bf* __restrict__ ctxb, const bf* __restrict__ woutproj,
    const float* __restrict__ out_proj_b, const float* __restrict__ tabb_f,
    bf* __restrict__ xbf, float* __restrict__ ssq, const bf* __restrict__ colb,
    const bf* __restrict__ wc1_t, const float* __restrict__ b_c1,
    const float* __restrict__ W_c2, float* __restrict__ outd) {
  int id = (blockIdx.x & 7) * 44 + (blockIdx.x >> 3);  // 352 = 8*44
  if (id < 96) {
    gemm_core(ctxb, woutproj, out_proj_b, xbf, nullptr, nullptr, nullptr, 0, 0,
              tabb_f, ssq, nullptr, id % 6, id / 6, Dc, 0, 4);
  } else {
    int r = id - 96;
    gemm_core(colb, wc1_t, b_c1, nullptr, nullptr, W_c2, outd, Tc, 9, nullptr,
              nullptr, nullptr, r % 2, r / 2, 256, 1, 3);
  }
}

// Launch D: t1 head with fused L2-norm scale (32 = 8*4 blocks).
__global__ __launch_bounds__(256) void gemm_t1(
    const bf* __restrict__ xbf, const bf* __restrict__ wt1_t,
    const float* __restrict__ b_t1, const float* __restrict__ W_t2,
    const float* __restrict__ ssq, float* __restrict__ outd) {
  int id = (blockIdx.x & 7) * 4 + (blockIdx.x >> 3);
  gemm_core(xbf, wt1_t, b_t1, nullptr, nullptr, W_t2, outd, 0, 6, nullptr,
            nullptr, ssq, id % 2, id / 2, 256, 1, 3);
}

// ---------------------------------------------------------------------------
// 3) Masked cross-attention: one block per (b,t), 8 heads x (4 col-groups x 8
//    lanes), vectorized bf16 loads. n==0 -> uniform over all C.
// ---------------------------------------------------------------------------
__global__ __launch_bounds__(256) void attn_kernel(
    const bf* __restrict__ q, const bf* __restrict__ kv,
    const int* __restrict__ col_sorted, const int* __restrict__ offs,
    bf* __restrict__ ctx) {
  int b = blockIdx.x / Tc;
  int t = blockIdx.x % Tc;
  __shared__ float pbuf[Hc][Cc];
  __shared__ float den[Hc];
  __shared__ int cols_s[Cc];
  int tid = threadIdx.x;
  int o0 = offs[b * (Tc + 1) + t];
  int n = offs[b * (Tc + 1) + t + 1] - o0;
  for (int i = tid; i < n; i += 256)
    cols_s[i] = col_sorted[(size_t)b * Cc + o0 + i];
  __syncthreads();
  int h = tid >> 5, l32 = tid & 31, g = l32 >> 3, i8 = l32 & 7;
  const float scale = 0.10206207261596577f;  // 1/sqrt(96)
  float q12[12];
  {
    const ushort* qp =
        (const ushort*)q + ((size_t)b * Tc + t) * Dc + h * DHc + i8 * 12;
    ushort4 u0 = *(const ushort4*)(qp);
    ushort4 u1 = *(const ushort4*)(qp + 4);
    ushort4 u2 = *(const ushort4*)(qp + 8);
    q12[0] = us2f(u0.x); q12[1] = us2f(u0.y); q12[2] = us2f(u0.z); q12[3] = us2f(u0.w);
    q12[4] = us2f(u1.x); q12[5] = us2f(u1.y); q12[6] = us2f(u1.z); q12[7] = us2f(u1.w);
    q12[8] = us2f(u2.x); q12[9] = us2f(u2.y); q12[10] = us2f(u2.z); q12[11] = us2f(u2.w);
  }
  if (n > 0) {
    for (int jb = 0; jb < n; jb += 4) {
      int j = jb + g;
      float s = 0.f;
      if (j < n) {
        const ushort* kp = (const ushort*)kv +
                           ((size_t)b * Cc + cols_s[j]) * 1536 + h * DHc + i8 * 12;
        ushort4 u0 = *(const ushort4*)(kp);
        ushort4 u1 = *(const ushort4*)(kp + 4);
        ushort4 u2 = *(const ushort4*)(kp + 8);
        s += q12[0] * us2f(u0.x) + q12[1] * us2f(u0.y) + q12[2] * us2f(u0.z) +
             q12[3] * us2f(u0.w);
        s += q12[4] * us2f(u1.x) + q12[5] * us2f(u1.y) + q12[6] * us2f(u1.z) +
             q12[7] * us2f(u1.w);
        s += q12[8] * us2f(u2.x) + q12[9] * us2f(u2.y) + q12[10] * us2f(u2.z) +
             q12[11] * us2f(u2.w);
      }
      s += __shfl_xor(s, 1);
      s += __shfl_xor(s, 2);
      s += __shfl_xor(s, 4);
      if (j < n && i8 == 0) pbuf[h][j] = s * scale;
    }
  }
  __syncthreads();
  if (n > 0) {
    float lmax = -3.0e38f;
    for (int j = l32; j < n; j += 32) lmax = fmaxf(lmax, pbuf[h][j]);
#pragma unroll
    for (int m = 16; m >= 1; m >>= 1) lmax = fmaxf(lmax, __shfl_xor(lmax, m));
    float lsum = 0.f;
    for (int j = l32; j < n; j += 32) {
      float e = __expf(pbuf[h][j] - lmax);
      pbuf[h][j] = e;
      lsum += e;
    }
#pragma unroll
    for (int m = 16; m >= 1; m >>= 1) lsum += __shfl_xor(lsum, m);
    if (l32 == 0) den[h] = lsum;
  } else if (l32 == 0) {
    den[h] = (float)Cc;
  }
  __syncthreads();
  int ncols = n > 0 ? n : Cc;
  float a12[12];
#pragma unroll
  for (int d = 0; d < 12; ++d) a12[d] = 0.f;
  for (int jb = 0; jb < ncols; jb += 4) {
    int j = jb + g;
    if (j < ncols) {
      int cj = n > 0 ? cols_s[j] : j;
      float pw = n > 0 ? pbuf[h][j] : 1.f;
      const ushort* vp = (const ushort*)kv + ((size_t)b * Cc + cj) * 1536 +
                         768 + h * DHc + i8 * 12;
      ushort4 u0 = *(const ushort4*)(vp);
      ushort4 u1 = *(const ushort4*)(vp + 4);
      ushort4 u2 = *(const ushort4*)(vp + 8);
      a12[0] += pw * us2f(u0.x); a12[1] += pw * us2f(u0.y);
      a12[2] += pw * us2f(u0.z); a12[3] += pw * us2f(u0.w);
      a12[4] += pw * us2f(u1.x); a12[5] += pw * us2f(u1.y);
      a12[6] += pw * us2f(u1.z); a12[7] += pw * us2f(u1.w);
      a12[8] += pw * us2f(u2.x); a12[9] += pw * us2f(u2.y);
      a12[10] += pw * us2f(u2.z); a12[11] += pw * us2f(u2.w);
    }
  }
#pragma unroll
  for (int d = 0; d < 12; ++d) {
    a12[d] += __shfl_xor(a12[d], 8);
    a12[d] += __shfl_xor(a12[d], 16);
  }
  float inv = 1.0f / den[h];
  if (g == 0) {
    ushort* cp = (ushort*)ctx + ((size_t)b * Tc + t) * Dc + h * DHc + i8 * 12;
    *(ushort4*)(cp) = make_ushort4(f2bf(a12[0] * inv), f2bf(a12[1] * inv),
                                   f2bf(a12[2] * inv), f2bf(a12[3] * inv));
    *(ushort4*)(cp + 4) = make_ushort4(f2bf(a12[4] * inv), f2bf(a12[5] * inv),
                                       f2bf(a12[6] * inv), f2bf(a12[7] * inv));
    *(ushort4*)(cp + 8) = make_ushort4(f2bf(a12[8] * inv), f2bf(a12[9] * inv),
                                       f2bf(a12[10] * inv), f2bf(a12[11] * inv));
  }
}

// ---------------------------------------------------------------------------
extern "C" void kernel_launch(void* const* d_in, const int* in_sizes, int n_in,
                              void* d_out, int out_size, void* d_ws,
                              size_t ws_size, hipStream_t stream) {
  const float* seq = (const float*)d_in[0];
  const int* tab_ids = (const int*)d_in[1];
  const int* col_ids = (const int*)d_in[2];
  const int* t_of_c = (const int*)d_in[3];
  const float* W_tab_pool = (const float*)d_in[4];
  const float* b_tab_pool = (const float*)d_in[5];
  const float* W_col_pool = (const float*)d_in[6];
  const float* b_col_pool = (const float*)d_in[7];
  const float* in_proj_w = (const float*)d_in[8];
  const float* in_proj_b = (const float*)d_in[9];
  const float* out_proj_w = (const float*)d_in[10];
  const float* out_proj_b = (const float*)d_in[11];
  const float* W_t1 = (const float*)d_in[12];
  const float* b_t1 = (const float*)d_in[13];
  const float* W_t2 = (const float*)d_in[14];
  const float* b_t2 = (const float*)d_in[15];
  const float* W_c1 = (const float*)d_in[16];
  const float* b_c1 = (const float*)d_in[17];
  const float* W_c2 = (const float*)d_in[18];
  const float* b_c2 = (const float*)d_in[19];
  float* out = (float*)d_out;

  char* p = (char*)d_ws;
  auto alloc = [&](size_t bytes) -> char* {
    char* r = p;
    p += (bytes + 255) & ~(size_t)255;
    return r;
  };
  const size_t nBT = (size_t)Bc * Tc;   // 2048
  const size_t nBC = (size_t)Bc * Cc;   // 16384
  ushort* seqb = (ushort*)alloc((size_t)Bc * Sc * Dc * 2);  // 100.7 MB
  bf* tabp = (bf*)alloc(nBT * Dc * 2);
  bf* colp = (bf*)alloc(nBC * Dc * 2);
  bf* tabb_bf = (bf*)alloc(nBT * Dc * 2);
  float* tabb_f = (float*)alloc(nBT * Dc * 4);
  bf* colb = (bf*)alloc(nBC * Dc * 2);
  bf* qb = (bf*)alloc(nBT * Dc * 2);
  bf* kvb = (bf*)alloc(nBC * 1536 * 2);
  bf* ctxb = (bf*)alloc(nBT * Dc * 2);
  bf* xbf = (bf*)alloc(nBT * Dc * 2);
  float* ssq = (float*)alloc(nBT * 4);
  bf* wtab_t = (bf*)alloc((size_t)Dc * Dc * 2);
  bf* wcol_t = (bf*)alloc((size_t)Dc * Dc * 2);
  bf* winproj = (bf*)alloc((size_t)3 * Dc * Dc * 2);
  bf* woutproj = (bf*)alloc((size_t)Dc * Dc * 2);
  bf* wt1_t = (bf*)alloc((size_t)256 * Dc * 2);
  bf* wc1_t = (bf*)alloc((size_t)256 * Dc * 2);
  int* col_sorted = (int*)alloc(nBC * 4);
  int* offs = (int*)alloc((size_t)Bc * (Tc + 1) * 4);

  // 1) prep: weights, out-init, seq->bf16, bucket, ssq-zero
  prep_kernel<<<28593, 256, 0, stream>>>(
      W_tab_pool, W_col_pool, W_t1, W_c1, in_proj_w, out_proj_w, b_t2, b_c2,
      seq, t_of_c, wtab_t, wcol_t, wt1_t, wc1_t, winproj, woutproj, out, seqb,
      col_sorted, offs, ssq);
  // 2) pooling (bf16 gather)
  pool_kernel<<<Bc * (Tc + Cc) / 4, 256, 0, stream>>>(seqb, tab_ids, col_ids,
                                                      (ushort*)tabp,
                                                      (ushort*)colp);
  // 3) pool linears (tab + col)
  gemm_pools<<<864, 256, 0, stream>>>(tabp, colp, wtab_t, wcol_t, b_tab_pool,
                                      b_col_pool, tabb_bf, tabb_f, colb);
  // 4) q + kv projections
  gemm_qkv<<<1632, 256, 0, stream>>>(tabb_bf, colb, winproj, in_proj_b, qb,
                                     kvb);
  // 5) attention
  attn_kernel<<<Bc * Tc, 256, 0, stream>>>(qb, kvb, col_sorted, offs, ctxb);
  // 6) outproj(+residual+norm-prep) co-scheduled with c1 head
  gemm_oc<<<352, 256, 0, stream>>>(ctxb, woutproj, out_proj_b, tabb_f, xbf,
                                   ssq, colb, wc1_t, b_c1, W_c2, out);
  // 7) t1 head with fused norm scale
  gemm_t1<<<32, 256, 0, stream>>>(xbf, wt1_t, b_t1, W_t2, ssq, out);
}